// Round 2
// baseline (4472.705 us; speedup 1.0000x reference)
//
#include <hip/hip_runtime.h>
#include <math.h>

// FNO1d: B=64, N=8192, F_IN=2, W=64, L=5, M=16, PAD=9 -> NLEN=8201
#define SROW 8208      // row stride (16-float aligned), >= NLEN
#define NLEN 8201
#define NB 64
#define W 64
#define M 16
#define NL 5
#define TWO_PI 6.283185307179586476925286766559

__device__ __forceinline__ float gelu_exact(float x) {
    return 0.5f * x * (1.0f + erff(x * 0.70710678118654752f));
}

// Build twiddle tables cosT[k][n], sinT[k][n] = cos/sin(2*pi*k*n/NLEN), fp64-accurate.
__global__ void ktable(float* __restrict__ cosT, float* __restrict__ sinT) {
    int n = blockIdx.x * 256 + threadIdx.x;
    int k = blockIdx.y;
    if (n >= SROW) return;
    long long m = ((long long)k * (long long)n) % NLEN;
    double th = (TWO_PI / (double)NLEN) * (double)m;
    double sv, cv;
    sincos(th, &sv, &cv);
    cosT[k * SROW + n] = (float)cv;
    sinT[k * SROW + n] = (float)sv;
}

// Transpose proj_w1 (64x128) -> w1t (128x64) for contiguous scalar loads.
__global__ void kw1t(const float* __restrict__ w1, float* __restrict__ w1t) {
    int idx = blockIdx.x * 256 + threadIdx.x;
    if (idx < 64 * 128) {
        int j = idx >> 6, i = idx & 63;
        w1t[idx] = w1[i * 128 + j];
    }
}

// Lift: v[b][w][n] = x[b][n][:]@lift_w + lift_b  (n<8192), 0 in pad region.
__global__ __launch_bounds__(256) void klift(const float* __restrict__ x,
        const float* __restrict__ lw, const float* __restrict__ lb,
        float* __restrict__ v) {
    int n = blockIdx.x * 256 + threadIdx.x;
    int b = blockIdx.y;
    if (n >= SROW) return;
    bool in = (n < 8192);
    float x0 = 0.f, x1 = 0.f;
    if (in) {
        const float2 xx = *(const float2*)(x + ((size_t)b * 8192 + n) * 2);
        x0 = xx.x; x1 = xx.y;
    }
    float* vp = v + (size_t)b * W * SROW + n;
    #pragma unroll
    for (int w = 0; w < W; w++) {
        float val = in ? fmaf(x0, lw[w], fmaf(x1, lw[W + w], lb[w])) : 0.f;
        vp[(size_t)w * SROW] = val;
    }
}

// Forward DFT, 16 modes: F[row][k] = sum_n v[row][n] * exp(-i*2pi*k*n/NLEN).
// Block handles 4 rows; thread strides n; twiddles via k-recurrence from table row k=1.
__global__ __launch_bounds__(256) void kdft(const float* __restrict__ v,
        const float* __restrict__ cosT, const float* __restrict__ sinT,
        float* __restrict__ F) {
    int row0 = blockIdx.x * 4;
    int t = threadIdx.x;
    float accR[4][16], accI[4][16];
    #pragma unroll
    for (int r = 0; r < 4; r++)
        #pragma unroll
        for (int k = 0; k < 16; k++) { accR[r][k] = 0.f; accI[r][k] = 0.f; }
    const float* v0 = v + (size_t)row0 * SROW;
    for (int n = t; n < NLEN; n += 256) {
        float c1 = cosT[SROW + n];
        float s1 = sinT[SROW + n];
        float vi[4];
        #pragma unroll
        for (int r = 0; r < 4; r++) vi[r] = v0[(size_t)r * SROW + n];
        #pragma unroll
        for (int r = 0; r < 4; r++) accR[r][0] += vi[r];
        float ck = c1, sk = s1;
        #pragma unroll
        for (int k = 1; k < 16; k++) {
            #pragma unroll
            for (int r = 0; r < 4; r++) {
                accR[r][k] = fmaf(vi[r], ck, accR[r][k]);
                accI[r][k] = fmaf(-vi[r], sk, accI[r][k]);
            }
            float cn = fmaf(ck, c1, -sk * s1);
            sk = fmaf(ck, s1, sk * c1);
            ck = cn;
        }
    }
    // wave butterfly reduce (64 lanes)
    #pragma unroll
    for (int r = 0; r < 4; r++)
        #pragma unroll
        for (int k = 0; k < 16; k++) {
            float xr = accR[r][k], xi = accI[r][k];
            #pragma unroll
            for (int off = 32; off > 0; off >>= 1) {
                xr += __shfl_down(xr, off, 64);
                xi += __shfl_down(xi, off, 64);
            }
            accR[r][k] = xr; accI[r][k] = xi;
        }
    __shared__ float red[4][128];
    int lane = t & 63, wv = t >> 6;
    if (lane == 0) {
        #pragma unroll
        for (int r = 0; r < 4; r++)
            #pragma unroll
            for (int k = 0; k < 16; k++) {
                red[wv][r * 32 + 2 * k]     = accR[r][k];
                red[wv][r * 32 + 2 * k + 1] = accI[r][k];
            }
    }
    __syncthreads();
    if (t < 128) {
        float sum = red[0][t] + red[1][t] + red[2][t] + red[3][t];
        int r = t >> 5, rem = t & 31, k = rem >> 1, comp = rem & 1;
        F[(((size_t)(row0 + r)) * M + k) * 2 + comp] = sum;
    }
}

// Mode mix: Pm[b][o][k] = sum_i F[b][i][k] * (kr+i*ki)[l][i][o][k], pre-scaled
// by 1/N (k=0) or 2/N (k>0) for the fused inverse transform.
__global__ void kmix(const float* __restrict__ F, const float* __restrict__ kr,
        const float* __restrict__ ki, float* __restrict__ Pm, int l) {
    int b = blockIdx.x;
    int kg = blockIdx.y;     // 0..3
    int o = threadIdx.x;     // 0..63
    #pragma unroll
    for (int kk = 0; kk < 4; kk++) {
        int k = kg * 4 + kk;
        float pr = 0.f, pi = 0.f;
        for (int i = 0; i < W; i++) {
            float fr = F[(((size_t)b * W + i) * M + k) * 2 + 0];
            float fi = F[(((size_t)b * W + i) * M + k) * 2 + 1];
            float krv = kr[(((size_t)l * W + i) * W + o) * M + k];
            float kiv = ki[(((size_t)l * W + i) * W + o) * M + k];
            pr += fr * krv - fi * kiv;
            pi += fr * kiv + fi * krv;
        }
        float sc = (k == 0) ? (1.0f / (float)NLEN) : (2.0f / (float)NLEN);
        Pm[(((size_t)b * W + o) * M + k) * 2 + 0] = pr * sc;
        Pm[(((size_t)b * W + o) * M + k) * 2 + 1] = pi * sc;
    }
}

// Fused: conv (64x64 per position) + inverse 16-mode transform + gelu.
// IN-PLACE on v: thread (b,n) reads column v[b][:][n] into registers, then
// writes the same column. Columns are thread-private -> no cross-thread hazard.
// Single pointer param (no restrict) so the compiler keeps load-before-store order.
__global__ __launch_bounds__(256) void kconv(float* v,
        const float* __restrict__ Pm, const float* __restrict__ cw,
        const float* __restrict__ cb, const float* __restrict__ cosT,
        const float* __restrict__ sinT, int l) {
    int n0 = blockIdx.x * 256 + threadIdx.x;
    int b = blockIdx.y;
    bool act = (n0 < NLEN);
    int n = act ? n0 : (NLEN - 1);
    float* vcol = v + (size_t)b * W * SROW + n;
    float vi[W];
    #pragma unroll
    for (int i = 0; i < W; i++) vi[i] = vcol[(size_t)i * SROW];
    float cs[15], sn[15];
    #pragma unroll
    for (int k = 1; k < 16; k++) {
        cs[k - 1] = cosT[k * SROW + n];
        sn[k - 1] = sinT[k * SROW + n];
    }
    const float* cwl = cw + (size_t)l * W * W;
    const float* cbl = cb + (size_t)l * W;
    const float* pmb = Pm + (size_t)b * W * M * 2;
    float res[W];
    for (int o = 0; o < W; o++) {
        float s = cbl[o];
        const float* cwo = cwl + o * W;
        #pragma unroll
        for (int i = 0; i < W; i++) s = fmaf(vi[i], cwo[i], s);
        const float* p = pmb + o * M * 2;
        float t = p[0];
        #pragma unroll
        for (int k = 1; k < 16; k++) {
            t = fmaf(p[2 * k], cs[k - 1], t);
            t = fmaf(-p[2 * k + 1], sn[k - 1], t);
        }
        res[o] = gelu_exact(s + t);
    }
    if (act) {
        #pragma unroll
        for (int o = 0; o < W; o++) vcol[(size_t)o * SROW] = res[o];
    }
}

// Final projection: out[b][n] = gelu(v[:,n]@W1 + b1) @ W2 + b2.
__global__ __launch_bounds__(256) void kproj(const float* __restrict__ vin,
        const float* __restrict__ w1t, const float* __restrict__ b1,
        const float* __restrict__ w2, const float* __restrict__ b2,
        float* __restrict__ out) {
    int n = blockIdx.x * 256 + threadIdx.x;   // 8192 exact
    int b = blockIdx.y;
    const float* vrow = vin + (size_t)b * W * SROW + n;
    float vi[W];
    #pragma unroll
    for (int i = 0; i < W; i++) vi[i] = vrow[(size_t)i * SROW];
    float acc = b2[0];
    for (int j = 0; j < 128; j++) {
        float s = b1[j];
        const float* wj = w1t + j * W;
        #pragma unroll
        for (int i = 0; i < W; i++) s = fmaf(vi[i], wj[i], s);
        acc = fmaf(gelu_exact(s), w2[j], acc);
    }
    out[(size_t)b * 8192 + n] = acc;
}

extern "C" void kernel_launch(void* const* d_in, const int* in_sizes, int n_in,
                              void* d_out, int out_size, void* d_ws, size_t ws_size,
                              hipStream_t stream) {
    const float* x  = (const float*)d_in[0];
    const float* lw = (const float*)d_in[1];
    const float* lb = (const float*)d_in[2];
    const float* kr = (const float*)d_in[3];
    const float* ki = (const float*)d_in[4];
    const float* cw = (const float*)d_in[5];
    const float* cb = (const float*)d_in[6];
    const float* w1 = (const float*)d_in[7];
    const float* b1 = (const float*)d_in[8];
    const float* w2 = (const float*)d_in[9];
    const float* b2 = (const float*)d_in[10];
    float* out = (float*)d_out;

    // workspace layout (floats), single v buffer (kconv is in-place):
    //   v    : 64*64*8208           = 33,619,968 f  (134.5 MB)
    //   cosT : 16*8208              =    131,328 f
    //   sinT : 16*8208              =    131,328 f
    //   F    : 64*64*16*2           =    131,072 f
    //   Pm   : 64*64*16*2           =    131,072 f
    //   w1t  : 128*64               =      8,192 f
    // total ~136.6 MB
    float* ws = (float*)d_ws;
    size_t vsz = (size_t)NB * W * SROW;
    float* v    = ws;
    float* cosT = v + vsz;
    float* sinT = cosT + (size_t)16 * SROW;
    float* F    = sinT + (size_t)16 * SROW;
    float* Pm   = F + (size_t)NB * W * M * 2;
    float* w1t  = Pm + (size_t)NB * W * M * 2;

    ktable<<<dim3(33, 16), 256, 0, stream>>>(cosT, sinT);
    kw1t<<<32, 256, 0, stream>>>(w1, w1t);
    klift<<<dim3(33, NB), 256, 0, stream>>>(x, lw, lb, v);

    for (int l = 0; l < NL; l++) {
        kdft<<<NB * W / 4, 256, 0, stream>>>(v, cosT, sinT, F);
        kmix<<<dim3(NB, 4), 64, 0, stream>>>(F, kr, ki, Pm, l);
        kconv<<<dim3(33, NB), 256, 0, stream>>>(v, Pm, cw, cb, cosT, sinT, l);
    }
    kproj<<<dim3(32, NB), 256, 0, stream>>>(v, w1t, b1, w2, b2, out);
}

// Round 3
// 2675.136 us; speedup vs baseline: 1.6720x; 1.6720x over previous
//
#include <hip/hip_runtime.h>
#include <math.h>

// FNO1d: B=64, N=8192, F_IN=2, W=64, L=5, M=16, PAD=9 -> NLEN=8201
#define SROW 8208      // row stride (16-float aligned), >= NLEN
#define NLEN 8201
#define NB 64
#define W 64
#define M 16
#define NL 5
#define TWO_PI 6.283185307179586476925286766559

__device__ __forceinline__ float gelu_exact(float x) {
    return 0.5f * x * (1.0f + erff(x * 0.70710678118654752f));
}

// Build twiddle tables cosT[k][n], sinT[k][n] = cos/sin(2*pi*k*n/NLEN), fp64-accurate.
__global__ void ktable(float* __restrict__ cosT, float* __restrict__ sinT) {
    int n = blockIdx.x * 256 + threadIdx.x;
    int k = blockIdx.y;
    if (n >= SROW) return;
    long long m = ((long long)k * (long long)n) % NLEN;
    double th = (TWO_PI / (double)NLEN) * (double)m;
    double sv, cv;
    sincos(th, &sv, &cv);
    cosT[k * SROW + n] = (float)cv;
    sinT[k * SROW + n] = (float)sv;
}

// Transpose proj_w1 (64x128) -> w1t (128x64) for contiguous staging loads.
__global__ void kw1t(const float* __restrict__ w1, float* __restrict__ w1t) {
    int idx = blockIdx.x * 256 + threadIdx.x;
    if (idx < 64 * 128) {
        int j = idx >> 6, i = idx & 63;
        w1t[idx] = w1[i * 128 + j];
    }
}

// Lift: v[b][w][n] = x[b][n][:]@lift_w + lift_b  (n<8192), 0 in pad region.
__global__ __launch_bounds__(256) void klift(const float* __restrict__ x,
        const float* __restrict__ lw, const float* __restrict__ lb,
        float* __restrict__ v) {
    int n = blockIdx.x * 256 + threadIdx.x;
    int b = blockIdx.y;
    if (n >= SROW) return;
    bool in = (n < 8192);
    float x0 = 0.f, x1 = 0.f;
    if (in) {
        const float2 xx = *(const float2*)(x + ((size_t)b * 8192 + n) * 2);
        x0 = xx.x; x1 = xx.y;
    }
    float* vp = v + (size_t)b * W * SROW + n;
    #pragma unroll
    for (int w = 0; w < W; w++) {
        float val = in ? fmaf(x0, lw[w], fmaf(x1, lw[W + w], lb[w])) : 0.f;
        vp[(size_t)w * SROW] = val;
    }
}

// Forward DFT, 16 modes: F[row][k] = sum_n v[row][n] * exp(-i*2pi*k*n/NLEN).
// Block handles 4 rows; thread strides n; twiddles via k-recurrence from table row k=1.
__global__ __launch_bounds__(256) void kdft(const float* __restrict__ v,
        const float* __restrict__ cosT, const float* __restrict__ sinT,
        float* __restrict__ F) {
    int row0 = blockIdx.x * 4;
    int t = threadIdx.x;
    float accR[4][16], accI[4][16];
    #pragma unroll
    for (int r = 0; r < 4; r++)
        #pragma unroll
        for (int k = 0; k < 16; k++) { accR[r][k] = 0.f; accI[r][k] = 0.f; }
    const float* v0 = v + (size_t)row0 * SROW;
    for (int n = t; n < NLEN; n += 256) {
        float c1 = cosT[SROW + n];
        float s1 = sinT[SROW + n];
        float vi[4];
        #pragma unroll
        for (int r = 0; r < 4; r++) vi[r] = v0[(size_t)r * SROW + n];
        #pragma unroll
        for (int r = 0; r < 4; r++) accR[r][0] += vi[r];
        float ck = c1, sk = s1;
        #pragma unroll
        for (int k = 1; k < 16; k++) {
            #pragma unroll
            for (int r = 0; r < 4; r++) {
                accR[r][k] = fmaf(vi[r], ck, accR[r][k]);
                accI[r][k] = fmaf(-vi[r], sk, accI[r][k]);
            }
            float cn = fmaf(ck, c1, -sk * s1);
            sk = fmaf(ck, s1, sk * c1);
            ck = cn;
        }
    }
    // wave butterfly reduce (64 lanes)
    #pragma unroll
    for (int r = 0; r < 4; r++)
        #pragma unroll
        for (int k = 0; k < 16; k++) {
            float xr = accR[r][k], xi = accI[r][k];
            #pragma unroll
            for (int off = 32; off > 0; off >>= 1) {
                xr += __shfl_down(xr, off, 64);
                xi += __shfl_down(xi, off, 64);
            }
            accR[r][k] = xr; accI[r][k] = xi;
        }
    __shared__ float red[4][128];
    int lane = t & 63, wv = t >> 6;
    if (lane == 0) {
        #pragma unroll
        for (int r = 0; r < 4; r++)
            #pragma unroll
            for (int k = 0; k < 16; k++) {
                red[wv][r * 32 + 2 * k]     = accR[r][k];
                red[wv][r * 32 + 2 * k + 1] = accI[r][k];
            }
    }
    __syncthreads();
    if (t < 128) {
        float sum = red[0][t] + red[1][t] + red[2][t] + red[3][t];
        int r = t >> 5, rem = t & 31, k = rem >> 1, comp = rem & 1;
        F[(((size_t)(row0 + r)) * M + k) * 2 + comp] = sum;
    }
}

// Mode mix: Pm[b][o][k] = sum_i F[b][i][k] * (kr+i*ki)[l][i][o][k], pre-scaled
// by 1/N (k=0) or 2/N (k>0) for the fused inverse transform.
__global__ void kmix(const float* __restrict__ F, const float* __restrict__ kr,
        const float* __restrict__ ki, float* __restrict__ Pm, int l) {
    int b = blockIdx.x;
    int kg = blockIdx.y;     // 0..3
    int o = threadIdx.x;     // 0..63
    #pragma unroll
    for (int kk = 0; kk < 4; kk++) {
        int k = kg * 4 + kk;
        float pr = 0.f, pi = 0.f;
        for (int i = 0; i < W; i++) {
            float fr = F[(((size_t)b * W + i) * M + k) * 2 + 0];
            float fi = F[(((size_t)b * W + i) * M + k) * 2 + 1];
            float krv = kr[(((size_t)l * W + i) * W + o) * M + k];
            float kiv = ki[(((size_t)l * W + i) * W + o) * M + k];
            pr += fr * krv - fi * kiv;
            pi += fr * kiv + fi * krv;
        }
        float sc = (k == 0) ? (1.0f / (float)NLEN) : (2.0f / (float)NLEN);
        Pm[(((size_t)b * W + o) * M + k) * 2 + 0] = pr * sc;
        Pm[(((size_t)b * W + o) * M + k) * 2 + 1] = pi * sc;
    }
}

// Fused conv + inverse 16-mode transform + gelu, IN-PLACE on v.
// Unified form: out[o] = sum_j Wext[o][j] * u[j], where
//   u = [ v[b][0..63][n], cos_1..15(n), sin_1..15(n), 1, 0 ]   (96 regs)
//   Wext[o][j] = cw[o][j]            j<64
//              = PmR[o][j-63]        j=64..78   (cos coeffs, k=1..15)
//              = -PmI[o][j-78]       j=79..93   (sin coeffs)
//              = cb[o]+PmR[o][0]     j=94       (constant term)
//              = 0                   j=95
// Wext (64x96 = 24 KB) staged in LDS once per block; inner reads are
// wave-uniform -> LDS broadcast, conflict-free. Store per-o immediately
// (no res[] array) -> ~110 VGPR -> 4 waves/SIMD.
__global__ __launch_bounds__(256) void kconv(float* v,
        const float* __restrict__ Pm, const float* __restrict__ cw,
        const float* __restrict__ cb, const float* __restrict__ cosT,
        const float* __restrict__ sinT, int l) {
    __shared__ __align__(16) float Wlds[64 * 96];
    int t = threadIdx.x;
    int n0 = blockIdx.x * 256 + t;
    int b = blockIdx.y;
    const float* cwl = cw + (size_t)l * W * W;
    const float* cbl = cb + (size_t)l * W;
    const float* pmb = Pm + (size_t)b * W * M * 2;

    // stage Wext
    #pragma unroll
    for (int it = 0; it < 24; it++) {
        int idx = t + it * 256;
        int o = idx / 96, j = idx - o * 96;
        float w;
        if (j < 64)       w = cwl[o * 64 + j];
        else if (j < 79)  w = pmb[(o * 16 + (j - 63)) * 2];
        else if (j < 94)  w = -pmb[(o * 16 + (j - 78)) * 2 + 1];
        else if (j == 94) w = cbl[o] + pmb[(o * 16) * 2];
        else              w = 0.f;
        Wlds[idx] = w;
    }

    bool act = (n0 < NLEN);
    int n = act ? n0 : (NLEN - 1);
    float* vcol = v + (size_t)b * W * SROW + n;
    float u[96];
    #pragma unroll
    for (int i = 0; i < 64; i++) u[i] = vcol[(size_t)i * SROW];
    #pragma unroll
    for (int k = 1; k < 16; k++) {
        u[63 + k] = cosT[k * SROW + n];
        u[78 + k] = sinT[k * SROW + n];
    }
    u[94] = 1.0f;
    u[95] = 0.0f;

    __syncthreads();

    for (int o = 0; o < 64; o++) {
        const float* wo = Wlds + o * 96;
        float acc = 0.f;
        #pragma unroll
        for (int j = 0; j < 96; j += 4) {
            float4 w4 = *(const float4*)(wo + j);
            acc = fmaf(u[j + 0], w4.x, acc);
            acc = fmaf(u[j + 1], w4.y, acc);
            acc = fmaf(u[j + 2], w4.z, acc);
            acc = fmaf(u[j + 3], w4.w, acc);
        }
        if (act) vcol[(size_t)o * SROW] = gelu_exact(acc);
    }
}

// Final projection: out[b][n] = gelu(v[:,n]@W1 + b1) @ W2 + b2.
// w1t (128x64 = 32 KB) + b1 + w2 staged in LDS; inner reads broadcast.
__global__ __launch_bounds__(256) void kproj(const float* __restrict__ vin,
        const float* __restrict__ w1t, const float* __restrict__ b1,
        const float* __restrict__ w2, const float* __restrict__ b2,
        float* __restrict__ out) {
    __shared__ __align__(16) float Wp[128 * 64];
    __shared__ float b1s[128], w2s[128];
    int t = threadIdx.x;
    int n = blockIdx.x * 256 + t;   // 8192 exact
    int b = blockIdx.y;
    #pragma unroll
    for (int it = 0; it < 32; it++) Wp[t + it * 256] = w1t[t + it * 256];
    if (t < 128) { b1s[t] = b1[t]; w2s[t] = w2[t]; }

    const float* vrow = vin + (size_t)b * W * SROW + n;
    float vi[W];
    #pragma unroll
    for (int i = 0; i < W; i++) vi[i] = vrow[(size_t)i * SROW];

    __syncthreads();

    float acc = b2[0];
    for (int j = 0; j < 128; j++) {
        const float* wj = Wp + j * 64;
        float s = b1s[j];
        #pragma unroll
        for (int i = 0; i < 64; i += 4) {
            float4 w4 = *(const float4*)(wj + i);
            s = fmaf(vi[i + 0], w4.x, s);
            s = fmaf(vi[i + 1], w4.y, s);
            s = fmaf(vi[i + 2], w4.z, s);
            s = fmaf(vi[i + 3], w4.w, s);
        }
        acc = fmaf(gelu_exact(s), w2s[j], acc);
    }
    out[(size_t)b * 8192 + n] = acc;
}

extern "C" void kernel_launch(void* const* d_in, const int* in_sizes, int n_in,
                              void* d_out, int out_size, void* d_ws, size_t ws_size,
                              hipStream_t stream) {
    const float* x  = (const float*)d_in[0];
    const float* lw = (const float*)d_in[1];
    const float* lb = (const float*)d_in[2];
    const float* kr = (const float*)d_in[3];
    const float* ki = (const float*)d_in[4];
    const float* cw = (const float*)d_in[5];
    const float* cb = (const float*)d_in[6];
    const float* w1 = (const float*)d_in[7];
    const float* b1 = (const float*)d_in[8];
    const float* w2 = (const float*)d_in[9];
    const float* b2 = (const float*)d_in[10];
    float* out = (float*)d_out;

    // workspace layout (floats), single v buffer (kconv is in-place):
    //   v    : 64*64*8208 = 33,619,968 f (134.5 MB)
    //   cosT/sinT : 16*8208 each; F/Pm : 64*64*16*2 each; w1t : 8192
    // total ~136.6 MB
    float* ws = (float*)d_ws;
    size_t vsz = (size_t)NB * W * SROW;
    float* v    = ws;
    float* cosT = v + vsz;
    float* sinT = cosT + (size_t)16 * SROW;
    float* F    = sinT + (size_t)16 * SROW;
    float* Pm   = F + (size_t)NB * W * M * 2;
    float* w1t  = Pm + (size_t)NB * W * M * 2;

    ktable<<<dim3(33, 16), 256, 0, stream>>>(cosT, sinT);
    kw1t<<<32, 256, 0, stream>>>(w1, w1t);
    klift<<<dim3(33, NB), 256, 0, stream>>>(x, lw, lb, v);

    for (int l = 0; l < NL; l++) {
        kdft<<<NB * W / 4, 256, 0, stream>>>(v, cosT, sinT, F);
        kmix<<<dim3(NB, 4), 64, 0, stream>>>(F, kr, ki, Pm, l);
        kconv<<<dim3(33, NB), 256, 0, stream>>>(v, Pm, cw, cb, cosT, sinT, l);
    }
    kproj<<<dim3(32, NB), 256, 0, stream>>>(v, w1t, b1, w2, b2, out);
}

// Round 4
// 2264.145 us; speedup vs baseline: 1.9755x; 1.1815x over previous
//
#include <hip/hip_runtime.h>
#include <math.h>

// FNO1d: B=64, N=8192, F_IN=2, W=64, L=5, M=16, PAD=9 -> NLEN=8201
#define SROW 8208      // row stride (16-float aligned), >= NLEN
#define NLEN 8201
#define NB 64
#define W 64
#define M 16
#define NL 5
#define TWO_PI 6.283185307179586476925286766559

__device__ __forceinline__ float gelu_exact(float x) {
    return 0.5f * x * (1.0f + erff(x * 0.70710678118654752f));
}

// Build twiddle tables cosT[k][n], sinT[k][n] = cos/sin(2*pi*k*n/NLEN), fp64-accurate.
__global__ void ktable(float* __restrict__ cosT, float* __restrict__ sinT) {
    int n = blockIdx.x * 256 + threadIdx.x;
    int k = blockIdx.y;
    if (n >= SROW) return;
    long long m = ((long long)k * (long long)n) % NLEN;
    double th = (TWO_PI / (double)NLEN) * (double)m;
    double sv, cv;
    sincos(th, &sv, &cv);
    cosT[k * SROW + n] = (float)cv;
    sinT[k * SROW + n] = (float)sv;
}

// Lift: v[b][w][n] = x[b][n][:]@lift_w + lift_b  (n<8192), 0 in pad region.
__global__ __launch_bounds__(256) void klift(const float* __restrict__ x,
        const float* __restrict__ lw, const float* __restrict__ lb,
        float* __restrict__ v) {
    int n = blockIdx.x * 256 + threadIdx.x;
    int b = blockIdx.y;
    if (n >= SROW) return;
    bool in = (n < 8192);
    float x0 = 0.f, x1 = 0.f;
    if (in) {
        const float2 xx = *(const float2*)(x + ((size_t)b * 8192 + n) * 2);
        x0 = xx.x; x1 = xx.y;
    }
    float* vp = v + (size_t)b * W * SROW + n;
    #pragma unroll
    for (int w = 0; w < W; w++) {
        float val = in ? fmaf(x0, lw[w], fmaf(x1, lw[W + w], lb[w])) : 0.f;
        vp[(size_t)w * SROW] = val;
    }
}

// Forward DFT, 16 modes, float4-vectorized over n. Block: 4 rows; thread strides
// 4-wide chunks; k-recurrence from table row k=1. Tail n=8200 by thread 0.
__global__ __launch_bounds__(256) void kdft(const float* __restrict__ v,
        const float* __restrict__ cosT, const float* __restrict__ sinT,
        float* __restrict__ F) {
    int row0 = blockIdx.x * 4;
    int t = threadIdx.x;
    float accR[4][16], accI[4][16];
    #pragma unroll
    for (int r = 0; r < 4; r++)
        #pragma unroll
        for (int k = 0; k < 16; k++) { accR[r][k] = 0.f; accI[r][k] = 0.f; }
    const float* v0 = v + (size_t)row0 * SROW;
    for (int c = t; c < 2050; c += 256) {   // n = 4c .. 4c+3, covers n<8200
        int n = c << 2;
        float4 c1 = *(const float4*)(cosT + SROW + n);
        float4 s1 = *(const float4*)(sinT + SROW + n);
        float4 vv[4];
        #pragma unroll
        for (int r = 0; r < 4; r++) vv[r] = *(const float4*)(v0 + (size_t)r * SROW + n);
        #pragma unroll
        for (int r = 0; r < 4; r++)
            accR[r][0] += (vv[r].x + vv[r].y) + (vv[r].z + vv[r].w);
        float4 ck = c1, sk = s1;
        #pragma unroll
        for (int k = 1; k < 16; k++) {
            #pragma unroll
            for (int r = 0; r < 4; r++) {
                float ar = accR[r][k];
                ar = fmaf(vv[r].x, ck.x, ar); ar = fmaf(vv[r].y, ck.y, ar);
                ar = fmaf(vv[r].z, ck.z, ar); ar = fmaf(vv[r].w, ck.w, ar);
                accR[r][k] = ar;
                float ai = accI[r][k];
                ai = fmaf(-vv[r].x, sk.x, ai); ai = fmaf(-vv[r].y, sk.y, ai);
                ai = fmaf(-vv[r].z, sk.z, ai); ai = fmaf(-vv[r].w, sk.w, ai);
                accI[r][k] = ai;
            }
            if (k < 15) {
                float4 cn, sn;
                cn.x = fmaf(ck.x, c1.x, -sk.x * s1.x); sn.x = fmaf(ck.x, s1.x, sk.x * c1.x);
                cn.y = fmaf(ck.y, c1.y, -sk.y * s1.y); sn.y = fmaf(ck.y, s1.y, sk.y * c1.y);
                cn.z = fmaf(ck.z, c1.z, -sk.z * s1.z); sn.z = fmaf(ck.z, s1.z, sk.z * c1.z);
                cn.w = fmaf(ck.w, c1.w, -sk.w * s1.w); sn.w = fmaf(ck.w, s1.w, sk.w * c1.w);
                ck = cn; sk = sn;
            }
        }
    }
    if (t == 0) {        // tail n = 8200
        int n = 8200;
        #pragma unroll
        for (int k = 0; k < 16; k++) {
            float cv = cosT[k * SROW + n], sv = sinT[k * SROW + n];
            #pragma unroll
            for (int r = 0; r < 4; r++) {
                float vr = v0[(size_t)r * SROW + n];
                accR[r][k] = fmaf(vr, cv, accR[r][k]);
                accI[r][k] = fmaf(-vr, sv, accI[r][k]);
            }
        }
    }
    // wave butterfly reduce (64 lanes)
    #pragma unroll
    for (int r = 0; r < 4; r++)
        #pragma unroll
        for (int k = 0; k < 16; k++) {
            float xr = accR[r][k], xi = accI[r][k];
            #pragma unroll
            for (int off = 32; off > 0; off >>= 1) {
                xr += __shfl_down(xr, off, 64);
                xi += __shfl_down(xi, off, 64);
            }
            accR[r][k] = xr; accI[r][k] = xi;
        }
    __shared__ float red[4][128];
    int lane = t & 63, wv = t >> 6;
    if (lane == 0) {
        #pragma unroll
        for (int r = 0; r < 4; r++)
            #pragma unroll
            for (int k = 0; k < 16; k++) {
                red[wv][r * 32 + 2 * k]     = accR[r][k];
                red[wv][r * 32 + 2 * k + 1] = accI[r][k];
            }
    }
    __syncthreads();
    if (t < 128) {
        float sum = red[0][t] + red[1][t] + red[2][t] + red[3][t];
        int r = t >> 5, rem = t & 31, k = rem >> 1, comp = rem & 1;
        F[(((size_t)(row0 + r)) * M + k) * 2 + comp] = sum;
    }
}

// Mode mix: Pm[b][o][k] = sum_i F[b][i][k]*(kr+i*ki)[l][i][o][k], scaled 1/N | 2/N.
// Grid (64 b, 4 kg) x 64 threads (o); float4 loads over k (coalesced-ish, L2-hot).
__global__ void kmix(const float* __restrict__ F, const float* __restrict__ kr,
        const float* __restrict__ ki, float* __restrict__ Pm, int l) {
    int b = blockIdx.x, kg = blockIdx.y;
    int o = threadIdx.x;
    const float* fb = F + (size_t)b * W * M * 2;
    const float* krl = kr + (size_t)l * W * W * M;
    const float* kil = ki + (size_t)l * W * W * M;
    float pr[4] = {0.f, 0.f, 0.f, 0.f}, pi[4] = {0.f, 0.f, 0.f, 0.f};
    for (int i = 0; i < W; i++) {
        float4 kr4 = *(const float4*)(krl + ((size_t)i * W + o) * M + kg * 4);
        float4 ki4 = *(const float4*)(kil + ((size_t)i * W + o) * M + kg * 4);
        float4 f0 = *(const float4*)(fb + ((size_t)i * M + kg * 4) * 2);      // re,im k0,k1
        float4 f1 = *(const float4*)(fb + ((size_t)i * M + kg * 4) * 2 + 4);  // re,im k2,k3
        pr[0] += f0.x * kr4.x - f0.y * ki4.x;  pi[0] += f0.x * ki4.x + f0.y * kr4.x;
        pr[1] += f0.z * kr4.y - f0.w * ki4.y;  pi[1] += f0.z * ki4.y + f0.w * kr4.y;
        pr[2] += f1.x * kr4.z - f1.y * ki4.z;  pi[2] += f1.x * ki4.z + f1.y * kr4.z;
        pr[3] += f1.z * kr4.w - f1.w * ki4.w;  pi[3] += f1.z * ki4.w + f1.w * kr4.w;
    }
    #pragma unroll
    for (int c = 0; c < 4; c++) {
        int k = kg * 4 + c;
        float sc = (k == 0) ? (1.0f / (float)NLEN) : (2.0f / (float)NLEN);
        Pm[((size_t)b * W + o) * M * 2 + k * 2 + 0] = pr[c] * sc;
        Pm[((size_t)b * W + o) * M * 2 + k * 2 + 1] = pi[c] * sc;
    }
}

// Fused conv + inverse transform + gelu, IN-PLACE, register-tiled GEMM.
// Block: 64o x 128n tile of one b. Thread: 8o x 4n (acc[8][4]).
// K=94 rows: u = [v rows 0..63, cos 1..15, sin 1..15]; bias+mode0 in acc init.
// W staged LDS-transposed Wlds[k][o] -> per-k frag = 2 broadcast b128 reads.
// u rows read as coalesced float4 straight from global (L1/L2-hot), no barrier.
__global__ __launch_bounds__(256) void kconv(float* v,
        const float* __restrict__ Pm, const float* __restrict__ cw,
        const float* __restrict__ cb, const float* __restrict__ cosT,
        const float* __restrict__ sinT, int l) {
    __shared__ __align__(16) float Wlds[94][64];   // 23.5 KB
    __shared__ float bias[64];
    int t = threadIdx.x;
    int b = blockIdx.y;
    int n0 = blockIdx.x * 128;
    const float* cwl = cw + (size_t)l * W * W;
    const float* pmb = Pm + (size_t)b * W * M * 2;
    #pragma unroll
    for (int it = 0; it < 24; it++) {
        int idx = t + it * 256;
        if (idx < 94 * 64) {
            int k = idx >> 6, o = idx & 63;
            float w;
            if (k < 64)      w = cwl[o * 64 + k];
            else if (k < 79) w = pmb[o * 32 + (k - 63) * 2];        // +PmR mode 1..15
            else             w = -pmb[o * 32 + (k - 78) * 2 + 1];   // -PmI mode 1..15
            Wlds[k][o] = w;
        }
    }
    if (t < 64) bias[t] = cb[l * W + t] + pmb[t * 32];   // cb + PmR mode0 (scaled)
    __syncthreads();

    int ln = t & 31;          // 32 n-groups of 4
    int og = t >> 5;          // 8 o-groups of 8
    int nn = n0 + ln * 4;
    float* vb = v + (size_t)b * W * SROW;
    float acc[8][4];
    #pragma unroll
    for (int r = 0; r < 8; r++) {
        float bs = bias[og * 8 + r];
        #pragma unroll
        for (int c = 0; c < 4; c++) acc[r][c] = bs;
    }

    #pragma unroll 4
    for (int k = 0; k < 64; k++) {
        float4 u = *(const float4*)(vb + (size_t)k * SROW + nn);
        float4 wa = *(const float4*)&Wlds[k][og * 8];
        float4 wb = *(const float4*)&Wlds[k][og * 8 + 4];
        float wr[8] = {wa.x, wa.y, wa.z, wa.w, wb.x, wb.y, wb.z, wb.w};
        #pragma unroll
        for (int r = 0; r < 8; r++) {
            acc[r][0] = fmaf(wr[r], u.x, acc[r][0]);
            acc[r][1] = fmaf(wr[r], u.y, acc[r][1]);
            acc[r][2] = fmaf(wr[r], u.z, acc[r][2]);
            acc[r][3] = fmaf(wr[r], u.w, acc[r][3]);
        }
    }
    #pragma unroll
    for (int k = 1; k <= 15; k++) {
        float4 u = *(const float4*)(cosT + (size_t)k * SROW + nn);
        float4 wa = *(const float4*)&Wlds[63 + k][og * 8];
        float4 wb = *(const float4*)&Wlds[63 + k][og * 8 + 4];
        float wr[8] = {wa.x, wa.y, wa.z, wa.w, wb.x, wb.y, wb.z, wb.w};
        #pragma unroll
        for (int r = 0; r < 8; r++) {
            acc[r][0] = fmaf(wr[r], u.x, acc[r][0]);
            acc[r][1] = fmaf(wr[r], u.y, acc[r][1]);
            acc[r][2] = fmaf(wr[r], u.z, acc[r][2]);
            acc[r][3] = fmaf(wr[r], u.w, acc[r][3]);
        }
    }
    #pragma unroll
    for (int k = 1; k <= 15; k++) {
        float4 u = *(const float4*)(sinT + (size_t)k * SROW + nn);
        float4 wa = *(const float4*)&Wlds[78 + k][og * 8];
        float4 wb = *(const float4*)&Wlds[78 + k][og * 8 + 4];
        float wr[8] = {wa.x, wa.y, wa.z, wa.w, wb.x, wb.y, wb.z, wb.w};
        #pragma unroll
        for (int r = 0; r < 8; r++) {
            acc[r][0] = fmaf(wr[r], u.x, acc[r][0]);
            acc[r][1] = fmaf(wr[r], u.y, acc[r][1]);
            acc[r][2] = fmaf(wr[r], u.z, acc[r][2]);
            acc[r][3] = fmaf(wr[r], u.w, acc[r][3]);
        }
    }

    if (nn < SROW) {   // last block covers only 16 columns
        #pragma unroll
        for (int r = 0; r < 8; r++) {
            float4 o4;
            o4.x = gelu_exact(acc[r][0]);
            o4.y = gelu_exact(acc[r][1]);
            o4.z = gelu_exact(acc[r][2]);
            o4.w = gelu_exact(acc[r][3]);
            *(float4*)(vb + (size_t)(og * 8 + r) * SROW + nn) = o4;
        }
    }
}

// Final projection, register-tiled: block = 128h x 128n of one b; thread 16h x 4n.
// Then per-thread partial dot with w2 + LDS reduction over 8 h-groups.
__global__ __launch_bounds__(256) void kproj(const float* __restrict__ v,
        const float* __restrict__ w1, const float* __restrict__ b1,
        const float* __restrict__ w2, const float* __restrict__ b2,
        float* __restrict__ out) {
    __shared__ __align__(16) float W1[64][128];     // W1[k][h] = w1[k*128+h], 32 KB
    __shared__ float b1s[128], w2s[128];
    __shared__ __align__(16) float red[32][9][4];   // padded mid-dim
    int t = threadIdx.x, b = blockIdx.y;
    int n0 = blockIdx.x * 128;
    #pragma unroll
    for (int it = 0; it < 32; it++) ((float*)W1)[t + it * 256] = w1[t + it * 256];
    if (t < 128) { b1s[t] = b1[t]; w2s[t] = w2[t]; }
    __syncthreads();

    int ln = t & 31, hg = t >> 5;
    int nn = n0 + ln * 4;
    const float* vb = v + (size_t)b * W * SROW;
    float acc[16][4];
    #pragma unroll
    for (int r = 0; r < 16; r++) {
        float bs = b1s[hg * 16 + r];
        #pragma unroll
        for (int c = 0; c < 4; c++) acc[r][c] = bs;
    }
    #pragma unroll 4
    for (int k = 0; k < 64; k++) {
        float4 u = *(const float4*)(vb + (size_t)k * SROW + nn);
        #pragma unroll
        for (int q = 0; q < 4; q++) {
            float4 w4 = *(const float4*)&W1[k][hg * 16 + q * 4];
            float wr[4] = {w4.x, w4.y, w4.z, w4.w};
            #pragma unroll
            for (int rr = 0; rr < 4; rr++) {
                int r = q * 4 + rr;
                acc[r][0] = fmaf(wr[rr], u.x, acc[r][0]);
                acc[r][1] = fmaf(wr[rr], u.y, acc[r][1]);
                acc[r][2] = fmaf(wr[rr], u.z, acc[r][2]);
                acc[r][3] = fmaf(wr[rr], u.w, acc[r][3]);
            }
        }
    }
    float p[4] = {0.f, 0.f, 0.f, 0.f};
    #pragma unroll
    for (int r = 0; r < 16; r++) {
        float wh = w2s[hg * 16 + r];
        #pragma unroll
        for (int c = 0; c < 4; c++) p[c] = fmaf(gelu_exact(acc[r][c]), wh, p[c]);
    }
    float4 p4 = {p[0], p[1], p[2], p[3]};
    *(float4*)&red[ln][hg][0] = p4;
    __syncthreads();
    if (t < 32) {
        float4 s = *(const float4*)&red[t][0][0];
        #pragma unroll
        for (int g = 1; g < 8; g++) {
            float4 q = *(const float4*)&red[t][g][0];
            s.x += q.x; s.y += q.y; s.z += q.z; s.w += q.w;
        }
        float bb = b2[0];
        s.x += bb; s.y += bb; s.z += bb; s.w += bb;
        *(float4*)(out + (size_t)b * 8192 + n0 + t * 4) = s;
    }
}

extern "C" void kernel_launch(void* const* d_in, const int* in_sizes, int n_in,
                              void* d_out, int out_size, void* d_ws, size_t ws_size,
                              hipStream_t stream) {
    const float* x  = (const float*)d_in[0];
    const float* lw = (const float*)d_in[1];
    const float* lb = (const float*)d_in[2];
    const float* kr = (const float*)d_in[3];
    const float* ki = (const float*)d_in[4];
    const float* cw = (const float*)d_in[5];
    const float* cb = (const float*)d_in[6];
    const float* w1 = (const float*)d_in[7];
    const float* b1 = (const float*)d_in[8];
    const float* w2 = (const float*)d_in[9];
    const float* b2 = (const float*)d_in[10];
    float* out = (float*)d_out;

    // workspace (floats): v 33,619,968 | cosT/sinT 131,328 ea | F/Pm 131,072 ea
    // total ~136.6 MB (same as R2's proven budget)
    float* ws = (float*)d_ws;
    size_t vsz = (size_t)NB * W * SROW;
    float* v    = ws;
    float* cosT = v + vsz;
    float* sinT = cosT + (size_t)16 * SROW;
    float* F    = sinT + (size_t)16 * SROW;
    float* Pm   = F + (size_t)NB * W * M * 2;

    ktable<<<dim3(33, 16), 256, 0, stream>>>(cosT, sinT);
    klift<<<dim3(33, NB), 256, 0, stream>>>(x, lw, lb, v);

    for (int l = 0; l < NL; l++) {
        kdft<<<NB * W / 4, 256, 0, stream>>>(v, cosT, sinT, F);
        kmix<<<dim3(NB, 4), 64, 0, stream>>>(F, kr, ki, Pm, l);
        kconv<<<dim3(65, NB), 256, 0, stream>>>(v, Pm, cw, cb, cosT, sinT, l);
    }
    kproj<<<dim3(64, NB), 256, 0, stream>>>(v, w1, b1, w2, b2, out);
}